// Round 3
// baseline (381.659 us; speedup 1.0000x reference)
//
#include <hip/hip_runtime.h>

#define B_ROWS 262144
#define T_COLS 80
#define STEPS 30
#define DT 0.1f
#define RPB 64           // rows per block = 1 wave, fully decoupled blocks
#define THREADS 64
#define LPAD 65          // [30][65] transposed: writes ~2-way (free), reads conflict-free

__global__ __launch_bounds__(THREADS) void traj_idm_kernel(
    const float* __restrict__ params,
    const float* __restrict__ sv_v1,
    const float* __restrict__ h1,
    const float* __restrict__ dv1,
    const float* __restrict__ sv_Y1,
    const float* __restrict__ lv_Y_seq1,
    const float* __restrict__ lv_v_seq1,
    float* __restrict__ out)
{
    __shared__ float sY[STEPS * LPAD];   // sY[s*65 + row]
    __shared__ float sV[STEPS * LPAD];

    const int t  = threadIdx.x;
    const int r0 = blockIdx.x * RPB;

    // --- irreducible col-49 gathers: issue first, overlap with staging ---
    const long gbase = (long)(r0 + t) * T_COLS + 49;
    const float v_i    = sv_v1 [gbase];
    const float gap_i  = h1    [gbase];
    const float delv_i = dv1   [gbase];
    const float y_i    = sv_Y1 [gbase];

    // --- coalesced staging: cols 48..79 (16B-aligned, 1KB contiguous per instr) ---
    // 64 rows x 8 float4 per array = 512 float4; 64 lanes -> 8 iters
    #pragma unroll
    for (int i = 0; i < 8; ++i) {
        const int idx = i * THREADS + t;       // 0..511
        const int row = idx >> 3;
        const int sub = idx & 7;
        const long goff = (long)(r0 + row) * T_COLS + 48 + sub * 4;
        const float4 ay = *(const float4*)(lv_Y_seq1 + goff);
        const float4 av = *(const float4*)(lv_v_seq1 + goff);
        const int cbase = sub * 4 - 2;         // s-index of component 0 (col 48+sub*4 -> s=col-50)
        #pragma unroll
        for (int j = 0; j < 4; ++j) {
            const int s = cbase + j;
            if (s >= 0) {                      // skip cols 48,49 (only sub==0, j<2)
                const float yv = j == 0 ? ay.x : j == 1 ? ay.y : j == 2 ? ay.z : ay.w;
                const float vv = j == 0 ? av.x : j == 1 ? av.y : j == 2 ? av.z : av.w;
                sY[s * LPAD + row] = yv;
                sV[s * LPAD + row] = vv;
            }
        }
    }
    __syncthreads();   // single-wave block: compiles to waitcnt + cheap barrier

    // --- compute: 30-step IDM recurrence, one thread per row ---
    const float s0   = params[0];
    const float Thw  = params[1];
    const float pa   = params[2];
    const float pb   = params[3];
    const float v0   = params[4];
    const float inv2sab = 1.0f / (2.0f * sqrtf(pa * pb));
    const float inv_v0  = 1.0f / v0;
    const float inv_dt  = 1.0f / DT;

    float v = v_i, gap = gap_i, delv = delv_i, y = y_i;
    float ys[STEPS];

    #pragma unroll
    for (int s = 0; s < STEPS; ++s) {
        const float lvY_i = sY[s * LPAD + t];   // conflict-free: consecutive lanes, consecutive addr
        const float lvv_i = sV[s * LPAD + t];

        const float s_star = s0 + fmaxf(v * Thw + v * delv * inv2sab, 0.0f);
        const float r  = v * inv_v0;
        const float r2 = r * r;
        const float q  = s_star / gap;
        const float a_calc = pa * (1.0f - r2 * r2 - q * q);
        const float v2 = v + a_calc * DT;
        const float a_t = (v2 <= 0.0f) ? (-v * inv_dt) : a_calc;

        v    = v + a_t * DT;
        delv = v - lvv_i;
        y    = y + v * DT;
        gap  = lvY_i - y;
        ys[s] = y;
    }

    // --- direct float2 stores (write-combining in L2 proven: WRITE_SIZE ideal) ---
    float2* __restrict__ o2 = (float2*)(out + (long)(r0 + t) * STEPS);
    #pragma unroll
    for (int p = 0; p < STEPS / 2; ++p) {
        float2 w;
        w.x = ys[2 * p];
        w.y = ys[2 * p + 1];
        o2[p] = w;
    }
}

extern "C" void kernel_launch(void* const* d_in, const int* in_sizes, int n_in,
                              void* d_out, int out_size, void* d_ws, size_t ws_size,
                              hipStream_t stream) {
    const float* params    = (const float*)d_in[0];
    const float* sv_v1     = (const float*)d_in[1];
    const float* h1        = (const float*)d_in[2];
    const float* dv1       = (const float*)d_in[3];
    const float* sv_Y1     = (const float*)d_in[4];
    const float* lv_Y_seq1 = (const float*)d_in[5];
    const float* lv_v_seq1 = (const float*)d_in[6];
    float* out = (float*)d_out;

    const int blocks = B_ROWS / RPB;   // 4096 single-wave blocks
    traj_idm_kernel<<<blocks, THREADS, 0, stream>>>(
        params, sv_v1, h1, dv1, sv_Y1, lv_Y_seq1, lv_v_seq1, out);
}